// Round 1
// baseline (375.045 us; speedup 1.0000x reference)
//
#include <hip/hip_runtime.h>
#include <stdint.h>

typedef unsigned long long u64;

#define M_DIM 16384
#define N_DIM 2048
#define K_DIM 2048
#define KC    32      // u64 chunks per row (K/64)
#define KT    16      // chunks per LDS stage

struct alignas(16) u64x2 { u64 x, y; };

// ---------------------------------------------------------------------------
// Pack kernel: one wave handles 256 consecutive floats (4 chunks of 64).
// Bit = 1 iff value < 0 (sign_fn: 0 -> +1, so strict < is correct).
// The lane->bit mapping is interleaved (k = 4*lane + e) but IDENTICAL for x
// and w, so XOR+popcount still computes the exact dot product.
// ---------------------------------------------------------------------------
__global__ __launch_bounds__(256) void pack_sign_kernel(
        const float* __restrict__ in, u64* __restrict__ out, int ngroups) {
    int wid  = (blockIdx.x * 256 + threadIdx.x) >> 6;   // global wave id
    int lane = threadIdx.x & 63;
    if (wid >= ngroups) return;
    const float4* p = reinterpret_cast<const float4*>(in) + (size_t)wid * 64 + lane;
    float4 v = *p;
    u64 b0 = __ballot(v.x < 0.0f);
    u64 b1 = __ballot(v.y < 0.0f);
    u64 b2 = __ballot(v.z < 0.0f);
    u64 b3 = __ballot(v.w < 0.0f);
    if (lane == 0) {
        u64* o = out + (size_t)wid * 4;
        o[0] = b0; o[1] = b1; o[2] = b2; o[3] = b3;
    }
}

// ---------------------------------------------------------------------------
// Binary GEMM: C[m][n] = K - 2*popcount(XOR of packed rows).
// Block tile 128x128, 256 threads, 8x8 outputs per lane.
// LDS tiles stored chunk-major ([chunk][row]) so each lane's fragment is a
// contiguous 64B run -> ds_read_b128s.
// ---------------------------------------------------------------------------
__global__ __launch_bounds__(256, 2) void bgemm_kernel(
        const u64* __restrict__ A,   // [M_DIM][KC]
        const u64* __restrict__ B,   // [N_DIM][KC]
        float* __restrict__ C) {     // [M_DIM][N_DIM]
    __shared__ u64 As[KT][128];
    __shared__ u64 Bs[KT][128];

    const int t     = threadIdx.x;
    const int m_blk = blockIdx.y << 7;
    const int n_blk = blockIdx.x << 7;

    const int lane = t & 63;
    const int wave = t >> 6;
    const int tm   = lane >> 3;      // 0..7
    const int tn   = lane & 7;       // 0..7
    const int m0   = ((wave >> 1) << 6) + (tm << 3);   // 0..120
    const int n0   = ((wave & 1) << 6) + (tn << 3);

    unsigned acc[8][8];
#pragma unroll
    for (int i = 0; i < 8; ++i)
#pragma unroll
        for (int j = 0; j < 8; ++j) acc[i][j] = 0u;

    const int sr = t >> 3;           // staging row base (0..31)
    const int sc = (t << 1) & 15;    // staging chunk (even)

    for (int ks = 0; ks < K_DIM / (KT * 64); ++ks) {   // 2 stages
        const int cbase = ks * KT;
        // Stage A and B tiles into LDS, transposed to [chunk][row].
        // Per iter: 8 threads cover one 128B row segment (coalesced).
#pragma unroll
        for (int i = 0; i < 4; ++i) {
            int r = i * 32 + sr;
            u64x2 va = *reinterpret_cast<const u64x2*>(
                A + (size_t)(m_blk + r) * KC + cbase + sc);
            As[sc][r]     = va.x;
            As[sc + 1][r] = va.y;
            u64x2 vb = *reinterpret_cast<const u64x2*>(
                B + (size_t)(n_blk + r) * KC + cbase + sc);
            Bs[sc][r]     = vb.x;
            Bs[sc + 1][r] = vb.y;
        }
        __syncthreads();

#pragma unroll 1
        for (int c = 0; c < KT; ++c) {
            u64 a[8], b[8];
#pragma unroll
            for (int i = 0; i < 4; ++i) {
                u64x2 va = *reinterpret_cast<const u64x2*>(&As[c][m0 + 2 * i]);
                a[2 * i]     = va.x;
                a[2 * i + 1] = va.y;
                u64x2 vb = *reinterpret_cast<const u64x2*>(&Bs[c][n0 + 2 * i]);
                b[2 * i]     = vb.x;
                b[2 * i + 1] = vb.y;
            }
#pragma unroll
            for (int i = 0; i < 8; ++i)
#pragma unroll
                for (int j = 0; j < 8; ++j)
                    acc[i][j] += (unsigned)__builtin_popcountll(a[i] ^ b[j]);
        }
        __syncthreads();
    }

    // Epilogue: C = K - 2*acc (exact integers), float4 stores.
#pragma unroll
    for (int i = 0; i < 8; ++i) {
        float* o = C + (size_t)(m_blk + m0 + i) * N_DIM + n_blk + n0;
        float4 v0, v1;
        v0.x = (float)(K_DIM - 2 * (int)acc[i][0]);
        v0.y = (float)(K_DIM - 2 * (int)acc[i][1]);
        v0.z = (float)(K_DIM - 2 * (int)acc[i][2]);
        v0.w = (float)(K_DIM - 2 * (int)acc[i][3]);
        v1.x = (float)(K_DIM - 2 * (int)acc[i][4]);
        v1.y = (float)(K_DIM - 2 * (int)acc[i][5]);
        v1.z = (float)(K_DIM - 2 * (int)acc[i][6]);
        v1.w = (float)(K_DIM - 2 * (int)acc[i][7]);
        *reinterpret_cast<float4*>(o)     = v0;
        *reinterpret_cast<float4*>(o + 4) = v1;
    }
}

extern "C" void kernel_launch(void* const* d_in, const int* in_sizes, int n_in,
                              void* d_out, int out_size, void* d_ws, size_t ws_size,
                              hipStream_t stream) {
    const float* x = (const float*)d_in[0];   // [M_DIM][K_DIM], values +/-1
    const float* w = (const float*)d_in[1];   // [N_DIM][K_DIM]
    float* out = (float*)d_out;               // [M_DIM][N_DIM]

    u64* xb = (u64*)d_ws;                     // 16384*32*8 = 4 MiB
    u64* wb = xb + (size_t)M_DIM * KC;        // + 512 KiB

    int xgroups = (M_DIM * K_DIM) / 256;      // 131072 waves
    int wgroups = (N_DIM * K_DIM) / 256;      // 16384 waves
    pack_sign_kernel<<<xgroups / 4, 256, 0, stream>>>(x, xb, xgroups);
    pack_sign_kernel<<<wgroups / 4, 256, 0, stream>>>(w, wb, wgroups);
    bgemm_kernel<<<dim3(N_DIM / 128, M_DIM / 128), 256, 0, stream>>>(xb, wb, out);
}

// Round 2
// 329.928 us; speedup vs baseline: 1.1367x; 1.1367x over previous
//
#include <hip/hip_runtime.h>
#include <stdint.h>

typedef unsigned long long u64;

#define M_DIM 16384
#define N_DIM 2048
#define K_DIM 2048

// ---------------- i8 MFMA path ----------------
#define BM 128
#define BN 256
#define BK 64
#define NSTAGE (K_DIM / BK)        // 32

typedef int v4i  __attribute__((ext_vector_type(4)));
typedef int v16i __attribute__((ext_vector_type(16)));

// Packed layouts (atom = 16 bytes = 16 k-values of one row):
//   A: [m_blk:128][s:32][c:2][t:4][kh:2][row:32] atoms   (8 KB / (m_blk,s))
//   B: [n_blk:8][s:32][c:2][t:8][kh:2][row:32] atoms    (16 KB / (n_blk,s))
// Atom (kh,row) sits at lane l = kh*32+row -> both global_load_lds staging and
// ds_read_b128 fragment reads are lane-linear (base + l*16): coalesced, no
// bank conflicts. MFMA A-frag: m=lane&31, k=(lane>>5)*16+j (CDNA family
// layout; any k-permutation cancels because A and B use identical packing).

__device__ __forceinline__ void gld16(void* lds_base, const void* gsrc) {
    __builtin_amdgcn_global_load_lds(
        (const __attribute__((address_space(1))) uint32_t*)gsrc,
        (__attribute__((address_space(3))) uint32_t*)lds_base,
        16, 0, 0);
}

__device__ __forceinline__ int pk4(float a, float b, float c, float d) {
    int r = (a < 0.0f ? 0xFF : 0x01);
    r |= (b < 0.0f ? 0xFF : 0x01) << 8;
    r |= (c < 0.0f ? 0xFF : 0x01) << 16;
    r |= (d < 0.0f ? 0xFF : 0x01) << 24;
    return r;
}

// One wave packs one (row-group, k-stage): 2*T regions of 1 KB.
// T = row-tiles per group (A: 4 -> 128 rows, B: 8 -> 256 rows).
template <int T>
__global__ __launch_bounds__(256) void pack_i8_kernel(
        const float* __restrict__ src, char* __restrict__ dst) {
    const int wave_id = (blockIdx.x * 256 + threadIdx.x) >> 6;
    const int lane = threadIdx.x & 63;
    const int s  = wave_id & (NSTAGE - 1);
    const int rg = wave_id >> 5;                  // NSTAGE == 32
    const int r  = lane & 31;
    const int kh = lane >> 5;
    const int regs = 2 * T;
    char* out = dst + ((size_t)rg * NSTAGE + s) * (regs * 1024) + lane * 16;
#pragma unroll 2
    for (int rr = 0; rr < regs; ++rr) {
        const int c = rr / T, t = rr % T;
        const int row = rg * (T * 32) + t * 32 + r;
        const float* p = src + (size_t)row * K_DIM + s * BK + c * 32 + kh * 16;
        const float4 v0 = ((const float4*)p)[0];
        const float4 v1 = ((const float4*)p)[1];
        const float4 v2 = ((const float4*)p)[2];
        const float4 v3 = ((const float4*)p)[3];
        int4 o;
        o.x = pk4(v0.x, v0.y, v0.z, v0.w);
        o.y = pk4(v1.x, v1.y, v1.z, v1.w);
        o.z = pk4(v2.x, v2.y, v2.z, v2.w);
        o.w = pk4(v3.x, v3.y, v3.z, v3.w);
        *(int4*)(out + rr * 1024) = o;
    }
}

__global__ __launch_bounds__(256, 2) void bgemm_i8_kernel(
        const char* __restrict__ Ap, const char* __restrict__ Bp,
        float* __restrict__ C) {
    __shared__ __align__(16) char As[8 * 1024];    // [c:2][t:4] regions
    __shared__ __align__(16) char Bs[16 * 1024];   // [c:2][t:8] regions

    const int t    = threadIdx.x;
    const int lane = t & 63;
    const int wv   = t >> 6;
    const int m_blk = blockIdx.y;                  // 0..127
    const int n_blk = blockIdx.x;                  // 0..7

    const int wm = (wv >> 1) * 2;                  // m-tile base: 0 or 2
    const int wn = (wv & 1) * 4;                   // n-tile base: 0 or 4

    const char* aS = Ap + (size_t)m_blk * (NSTAGE * 8192);
    const char* bS = Bp + (size_t)n_blk * (NSTAGE * 16384);

    v16i acc[2][4];
#pragma unroll
    for (int i = 0; i < 2; ++i)
#pragma unroll
        for (int j = 0; j < 4; ++j)
#pragma unroll
            for (int q = 0; q < 16; ++q) acc[i][j][q] = 0;

    const int wv6 = wv * 6;
    for (int s = 0; s < NSTAGE; ++s) {
        // Stage 24 regions (8 A + 16 B), 6 per wave, all lane-linear 1 KB.
#pragma unroll
        for (int r = 0; r < 6; ++r) {
            const int reg = wv6 + r;
            const bool isA = reg < 8;
            const char* g = isA ? (aS + reg * 1024) : (bS + (reg - 8) * 1024);
            char* l = isA ? (As + reg * 1024) : (Bs + (reg - 8) * 1024);
            gld16(l, g + lane * 16);
        }
        aS += 8192;
        bS += 16384;
        __syncthreads();   // vmcnt(0) drain: staged data visible to all

#pragma unroll
        for (int c = 0; c < 2; ++c) {
            v4i af[2], bf[4];
#pragma unroll
            for (int i = 0; i < 2; ++i)
                af[i] = *(const v4i*)(As + (c * 4 + wm + i) * 1024 + lane * 16);
#pragma unroll
            for (int j = 0; j < 4; ++j)
                bf[j] = *(const v4i*)(Bs + (c * 8 + wn + j) * 1024 + lane * 16);
#pragma unroll
            for (int i = 0; i < 2; ++i)
#pragma unroll
                for (int j = 0; j < 4; ++j)
                    acc[i][j] = __builtin_amdgcn_mfma_i32_32x32x32_i8(
                        af[i], bf[j], acc[i][j], 0, 0, 0);
        }
        __syncthreads();   // LDS free for next stage's DMA
    }

    // C/D layout (HW-measured, dtype-independent):
    //   col = lane&31, row = (q&3) + 8*(q>>2) + 4*(lane>>5)
    const int col = lane & 31;
    const int rq  = (lane >> 5) * 4;
#pragma unroll
    for (int i = 0; i < 2; ++i) {
#pragma unroll
        for (int j = 0; j < 4; ++j) {
            const int mbase = m_blk * BM + (wm + i) * 32;
            const int nbase = n_blk * BN + (wn + j) * 32;
#pragma unroll
            for (int q = 0; q < 16; ++q) {
                const int row = mbase + (q & 3) + 8 * (q >> 2) + rq;
                C[(size_t)row * N_DIM + nbase + col] = (float)acc[i][j][q];
            }
        }
    }
}

// ---------------- fallback: u64 XOR-popcount path (R1, known-good) ----------
#define KC 32
#define KT 16
struct alignas(16) u64x2 { u64 x, y; };

__global__ __launch_bounds__(256) void pack_sign_kernel(
        const float* __restrict__ in, u64* __restrict__ out, int ngroups) {
    int wid  = (blockIdx.x * 256 + threadIdx.x) >> 6;
    int lane = threadIdx.x & 63;
    if (wid >= ngroups) return;
    const float4* p = reinterpret_cast<const float4*>(in) + (size_t)wid * 64 + lane;
    float4 v = *p;
    u64 b0 = __ballot(v.x < 0.0f);
    u64 b1 = __ballot(v.y < 0.0f);
    u64 b2 = __ballot(v.z < 0.0f);
    u64 b3 = __ballot(v.w < 0.0f);
    if (lane == 0) {
        u64* o = out + (size_t)wid * 4;
        o[0] = b0; o[1] = b1; o[2] = b2; o[3] = b3;
    }
}

__global__ __launch_bounds__(256, 2) void bgemm_kernel(
        const u64* __restrict__ A, const u64* __restrict__ B,
        float* __restrict__ C) {
    __shared__ u64 As[KT][128];
    __shared__ u64 Bs[KT][128];
    const int t     = threadIdx.x;
    const int m_blk = blockIdx.y << 7;
    const int n_blk = blockIdx.x << 7;
    const int lane = t & 63;
    const int wave = t >> 6;
    const int tm   = lane >> 3;
    const int tn   = lane & 7;
    const int m0   = ((wave >> 1) << 6) + (tm << 3);
    const int n0   = ((wave & 1) << 6) + (tn << 3);
    unsigned acc[8][8];
#pragma unroll
    for (int i = 0; i < 8; ++i)
#pragma unroll
        for (int j = 0; j < 8; ++j) acc[i][j] = 0u;
    const int sr = t >> 3;
    const int sc = (t << 1) & 15;
    for (int ks = 0; ks < K_DIM / (KT * 64); ++ks) {
        const int cbase = ks * KT;
#pragma unroll
        for (int i = 0; i < 4; ++i) {
            int r = i * 32 + sr;
            u64x2 va = *reinterpret_cast<const u64x2*>(A + (size_t)(m_blk + r) * KC + cbase + sc);
            As[sc][r] = va.x; As[sc + 1][r] = va.y;
            u64x2 vb = *reinterpret_cast<const u64x2*>(B + (size_t)(n_blk + r) * KC + cbase + sc);
            Bs[sc][r] = vb.x; Bs[sc + 1][r] = vb.y;
        }
        __syncthreads();
#pragma unroll 1
        for (int c = 0; c < KT; ++c) {
            u64 a[8], b[8];
#pragma unroll
            for (int i = 0; i < 4; ++i) {
                u64x2 va = *reinterpret_cast<const u64x2*>(&As[c][m0 + 2 * i]);
                a[2 * i] = va.x; a[2 * i + 1] = va.y;
                u64x2 vb = *reinterpret_cast<const u64x2*>(&Bs[c][n0 + 2 * i]);
                b[2 * i] = vb.x; b[2 * i + 1] = vb.y;
            }
#pragma unroll
            for (int i = 0; i < 8; ++i)
#pragma unroll
                for (int j = 0; j < 8; ++j)
                    acc[i][j] += (unsigned)__builtin_popcountll(a[i] ^ b[j]);
        }
        __syncthreads();
    }
#pragma unroll
    for (int i = 0; i < 8; ++i) {
        float* o = C + (size_t)(m_blk + m0 + i) * N_DIM + n_blk + n0;
        float4 v0, v1;
        v0.x = (float)(K_DIM - 2 * (int)acc[i][0]);
        v0.y = (float)(K_DIM - 2 * (int)acc[i][1]);
        v0.z = (float)(K_DIM - 2 * (int)acc[i][2]);
        v0.w = (float)(K_DIM - 2 * (int)acc[i][3]);
        v1.x = (float)(K_DIM - 2 * (int)acc[i][4]);
        v1.y = (float)(K_DIM - 2 * (int)acc[i][5]);
        v1.z = (float)(K_DIM - 2 * (int)acc[i][6]);
        v1.w = (float)(K_DIM - 2 * (int)acc[i][7]);
        *reinterpret_cast<float4*>(o)     = v0;
        *reinterpret_cast<float4*>(o + 4) = v1;
    }
}

extern "C" void kernel_launch(void* const* d_in, const int* in_sizes, int n_in,
                              void* d_out, int out_size, void* d_ws, size_t ws_size,
                              hipStream_t stream) {
    const float* x = (const float*)d_in[0];
    const float* w = (const float*)d_in[1];
    float* out = (float*)d_out;

    const size_t needA = (size_t)M_DIM * K_DIM;          // 32 MiB packed i8 A
    const size_t needB = (size_t)N_DIM * K_DIM;          // 4 MiB packed i8 B
    if (ws_size >= needA + needB) {
        char* Ap = (char*)d_ws;
        char* Bp = Ap + needA;
        // A: 128 row-groups x 32 stages = 4096 waves; B: 8 x 32 = 256 waves
        pack_i8_kernel<4><<<4096 / 4, 256, 0, stream>>>(x, Ap);
        pack_i8_kernel<8><<<256 / 4, 256, 0, stream>>>(w, Bp);
        bgemm_i8_kernel<<<dim3(N_DIM / BN, M_DIM / BM), 256, 0, stream>>>(Ap, Bp, out);
    } else {
        u64* xb = (u64*)d_ws;
        u64* wb = xb + (size_t)M_DIM * KC;
        int xgroups = (M_DIM * K_DIM) / 256;
        int wgroups = (N_DIM * K_DIM) / 256;
        pack_sign_kernel<<<xgroups / 4, 256, 0, stream>>>(x, xb, xgroups);
        pack_sign_kernel<<<wgroups / 4, 256, 0, stream>>>(w, wb, wgroups);
        bgemm_kernel<<<dim3(N_DIM / 128, M_DIM / 128), 256, 0, stream>>>(xb, wb, out);
    }
}

// Round 3
// 315.413 us; speedup vs baseline: 1.1891x; 1.0460x over previous
//
#include <hip/hip_runtime.h>
#include <stdint.h>

typedef unsigned long long u64;

#define M_DIM 16384
#define N_DIM 2048
#define K_DIM 2048

// ---------------- i8 MFMA path ----------------
#define BM 128
#define BN 256
#define BK 64
#define NSTAGE (K_DIM / BK)        // 32

typedef int v4i  __attribute__((ext_vector_type(4)));
typedef int v16i __attribute__((ext_vector_type(16)));

// Packed layouts (atom = 16 bytes = 16 k-values of one row):
//   A: [m_blk:128][s:32][c:2][t:4][kh:2][row:32] atoms   (8 KB / (m_blk,s))
//   B: [n_blk:8][s:32][c:2][t:8][kh:2][row:32] atoms    (16 KB / (n_blk,s))
// Atom (kh,row) sits at lane l = kh*32+row -> both global_load_lds staging and
// ds_read_b128 fragment reads are lane-linear (base + l*16): coalesced, zero
// bank conflicts (verified R2: SQ_LDS_BANK_CONFLICT == 0). k-permutation
// inside fragments cancels because A and B use identical packing.

__device__ __forceinline__ void gld16(void* lds_base, const void* gsrc) {
    __builtin_amdgcn_global_load_lds(
        (const __attribute__((address_space(1))) uint32_t*)gsrc,
        (__attribute__((address_space(3))) uint32_t*)lds_base,
        16, 0, 0);
}

__device__ __forceinline__ int pk4(float a, float b, float c, float d) {
    int r = (a < 0.0f ? 0xFF : 0x01);
    r |= (b < 0.0f ? 0xFF : 0x01) << 8;
    r |= (c < 0.0f ? 0xFF : 0x01) << 16;
    r |= (d < 0.0f ? 0xFF : 0x01) << 24;
    return r;
}

template <int T>
__global__ __launch_bounds__(256) void pack_i8_kernel(
        const float* __restrict__ src, char* __restrict__ dst) {
    const int wave_id = (blockIdx.x * 256 + threadIdx.x) >> 6;
    const int lane = threadIdx.x & 63;
    const int s  = wave_id & (NSTAGE - 1);
    const int rg = wave_id >> 5;                  // NSTAGE == 32
    const int r  = lane & 31;
    const int kh = lane >> 5;
    const int regs = 2 * T;
    char* out = dst + ((size_t)rg * NSTAGE + s) * (regs * 1024) + lane * 16;
#pragma unroll 2
    for (int rr = 0; rr < regs; ++rr) {
        const int c = rr / T, t = rr % T;
        const int row = rg * (T * 32) + t * 32 + r;
        const float* p = src + (size_t)row * K_DIM + s * BK + c * 32 + kh * 16;
        const float4 v0 = ((const float4*)p)[0];
        const float4 v1 = ((const float4*)p)[1];
        const float4 v2 = ((const float4*)p)[2];
        const float4 v3 = ((const float4*)p)[3];
        int4 o;
        o.x = pk4(v0.x, v0.y, v0.z, v0.w);
        o.y = pk4(v1.x, v1.y, v1.z, v1.w);
        o.z = pk4(v2.x, v2.y, v2.z, v2.w);
        o.w = pk4(v3.x, v3.y, v3.z, v3.w);
        *(int4*)(out + rr * 1024) = o;
    }
}

// Double-buffered K-loop: prefetch stage s+1 into the other LDS buffer BEFORE
// computing stage s; single __syncthreads per stage. The barrier's implicit
// vmcnt(0) drain then waits on DMAs that were issued ~1170 compute-cycles
// earlier (mostly complete), instead of fully exposing the ~600-1900 cycle
// staging latency as in the R2 2-barrier structure.
__global__ __launch_bounds__(256, 2) void bgemm_i8_kernel(
        const char* __restrict__ Ap, const char* __restrict__ Bp,
        float* __restrict__ C) {
    // buffer = [A: 8 regions][B: 16 regions] of 1 KB; two buffers = 48 KB.
    __shared__ __align__(16) char lds[2][24 * 1024];

    const int t    = threadIdx.x;
    const int lane = t & 63;
    const int wv   = t >> 6;
    const int m_blk = blockIdx.y;                  // 0..127
    const int n_blk = blockIdx.x;                  // 0..7

    const int wm = (wv >> 1) * 2;                  // m-tile base: 0 or 2
    const int wn = (wv & 1) * 4;                   // n-tile base: 0 or 4

    const char* aBase = Ap + (size_t)m_blk * (NSTAGE * 8192);
    const char* bBase = Bp + (size_t)n_blk * (NSTAGE * 16384);
    const int wv6 = wv * 6;

    v16i acc[2][4];
#pragma unroll
    for (int i = 0; i < 2; ++i)
#pragma unroll
        for (int j = 0; j < 4; ++j)
#pragma unroll
            for (int q = 0; q < 16; ++q) acc[i][j][q] = 0;

    auto stage = [&](int s, int buf) {
        const char* a = aBase + (size_t)s * 8192;
        const char* b = bBase + (size_t)s * 16384;
        char* l = lds[buf];
#pragma unroll
        for (int r = 0; r < 6; ++r) {
            const int reg = wv6 + r;
            const bool isA = reg < 8;
            const char* g = isA ? (a + reg * 1024) : (b + (reg - 8) * 1024);
            gld16(l + reg * 1024, g + lane * 16);
        }
    };

    auto compute = [&](int buf) {
        const char* As = lds[buf];
        const char* Bs = lds[buf] + 8192;
#pragma unroll
        for (int c = 0; c < 2; ++c) {
            v4i af[2], bf[4];
#pragma unroll
            for (int i = 0; i < 2; ++i)
                af[i] = *(const v4i*)(As + (c * 4 + wm + i) * 1024 + lane * 16);
#pragma unroll
            for (int j = 0; j < 4; ++j)
                bf[j] = *(const v4i*)(Bs + (c * 8 + wn + j) * 1024 + lane * 16);
#pragma unroll
            for (int i = 0; i < 2; ++i)
#pragma unroll
                for (int j = 0; j < 4; ++j)
                    acc[i][j] = __builtin_amdgcn_mfma_i32_32x32x32_i8(
                        af[i], bf[j], acc[i][j], 0, 0, 0);
        }
    };

    stage(0, 0);
    __syncthreads();                     // one-time prologue drain
#pragma unroll 1
    for (int s = 0; s < NSTAGE; s += 2) {
        if (s + 1 < NSTAGE) stage(s + 1, 1);   // prefetch (in flight during compute)
        compute(0);
        __syncthreads();                 // drains s+1 DMA + frees buf0 readers
        if (s + 2 < NSTAGE) stage(s + 2, 0);
        compute(1);
        __syncthreads();
    }

    // C/D layout (HW-measured, dtype-independent):
    //   col = lane&31, row = (q&3) + 8*(q>>2) + 4*(lane>>5)
    const int col = lane & 31;
    const int rq  = (lane >> 5) * 4;
#pragma unroll
    for (int i = 0; i < 2; ++i) {
#pragma unroll
        for (int j = 0; j < 4; ++j) {
            const int mbase = m_blk * BM + (wm + i) * 32;
            const int nbase = n_blk * BN + (wn + j) * 32;
#pragma unroll
            for (int q = 0; q < 16; ++q) {
                const int row = mbase + (q & 3) + 8 * (q >> 2) + rq;
                C[(size_t)row * N_DIM + nbase + col] = (float)acc[i][j][q];
            }
        }
    }
}

// ---------------- fallback: u64 XOR-popcount path (R1, known-good) ----------
#define KC 32
#define KT 16
struct alignas(16) u64x2 { u64 x, y; };

__global__ __launch_bounds__(256) void pack_sign_kernel(
        const float* __restrict__ in, u64* __restrict__ out, int ngroups) {
    int wid  = (blockIdx.x * 256 + threadIdx.x) >> 6;
    int lane = threadIdx.x & 63;
    if (wid >= ngroups) return;
    const float4* p = reinterpret_cast<const float4*>(in) + (size_t)wid * 64 + lane;
    float4 v = *p;
    u64 b0 = __ballot(v.x < 0.0f);
    u64 b1 = __ballot(v.y < 0.0f);
    u64 b2 = __ballot(v.z < 0.0f);
    u64 b3 = __ballot(v.w < 0.0f);
    if (lane == 0) {
        u64* o = out + (size_t)wid * 4;
        o[0] = b0; o[1] = b1; o[2] = b2; o[3] = b3;
    }
}

__global__ __launch_bounds__(256, 2) void bgemm_kernel(
        const u64* __restrict__ A, const u64* __restrict__ B,
        float* __restrict__ C) {
    __shared__ u64 As[KT][128];
    __shared__ u64 Bs[KT][128];
    const int t     = threadIdx.x;
    const int m_blk = blockIdx.y << 7;
    const int n_blk = blockIdx.x << 7;
    const int lane = t & 63;
    const int wave = t >> 6;
    const int tm   = lane >> 3;
    const int tn   = lane & 7;
    const int m0   = ((wave >> 1) << 6) + (tm << 3);
    const int n0   = ((wave & 1) << 6) + (tn << 3);
    unsigned acc[8][8];
#pragma unroll
    for (int i = 0; i < 8; ++i)
#pragma unroll
        for (int j = 0; j < 8; ++j) acc[i][j] = 0u;
    const int sr = t >> 3;
    const int sc = (t << 1) & 15;
    for (int ks = 0; ks < K_DIM / (KT * 64); ++ks) {
        const int cbase = ks * KT;
#pragma unroll
        for (int i = 0; i < 4; ++i) {
            int r = i * 32 + sr;
            u64x2 va = *reinterpret_cast<const u64x2*>(A + (size_t)(m_blk + r) * KC + cbase + sc);
            As[sc][r] = va.x; As[sc + 1][r] = va.y;
            u64x2 vb = *reinterpret_cast<const u64x2*>(B + (size_t)(n_blk + r) * KC + cbase + sc);
            Bs[sc][r] = vb.x; Bs[sc + 1][r] = vb.y;
        }
        __syncthreads();
#pragma unroll 1
        for (int c = 0; c < KT; ++c) {
            u64 a[8], b[8];
#pragma unroll
            for (int i = 0; i < 4; ++i) {
                u64x2 va = *reinterpret_cast<const u64x2*>(&As[c][m0 + 2 * i]);
                a[2 * i] = va.x; a[2 * i + 1] = va.y;
                u64x2 vb = *reinterpret_cast<const u64x2*>(&Bs[c][n0 + 2 * i]);
                b[2 * i] = vb.x; b[2 * i + 1] = vb.y;
            }
#pragma unroll
            for (int i = 0; i < 8; ++i)
#pragma unroll
                for (int j = 0; j < 8; ++j)
                    acc[i][j] += (unsigned)__builtin_popcountll(a[i] ^ b[j]);
        }
        __syncthreads();
    }
#pragma unroll
    for (int i = 0; i < 8; ++i) {
        float* o = C + (size_t)(m_blk + m0 + i) * N_DIM + n_blk + n0;
        float4 v0, v1;
        v0.x = (float)(K_DIM - 2 * (int)acc[i][0]);
        v0.y = (float)(K_DIM - 2 * (int)acc[i][1]);
        v0.z = (float)(K_DIM - 2 * (int)acc[i][2]);
        v0.w = (float)(K_DIM - 2 * (int)acc[i][3]);
        v1.x = (float)(K_DIM - 2 * (int)acc[i][4]);
        v1.y = (float)(K_DIM - 2 * (int)acc[i][5]);
        v1.z = (float)(K_DIM - 2 * (int)acc[i][6]);
        v1.w = (float)(K_DIM - 2 * (int)acc[i][7]);
        *reinterpret_cast<float4*>(o)     = v0;
        *reinterpret_cast<float4*>(o + 4) = v1;
    }
}

extern "C" void kernel_launch(void* const* d_in, const int* in_sizes, int n_in,
                              void* d_out, int out_size, void* d_ws, size_t ws_size,
                              hipStream_t stream) {
    const float* x = (const float*)d_in[0];
    const float* w = (const float*)d_in[1];
    float* out = (float*)d_out;

    const size_t needA = (size_t)M_DIM * K_DIM;          // 32 MiB packed i8 A
    const size_t needB = (size_t)N_DIM * K_DIM;          // 4 MiB packed i8 B
    if (ws_size >= needA + needB) {
        char* Ap = (char*)d_ws;
        char* Bp = Ap + needA;
        pack_i8_kernel<4><<<4096 / 4, 256, 0, stream>>>(x, Ap);
        pack_i8_kernel<8><<<256 / 4, 256, 0, stream>>>(w, Bp);
        bgemm_i8_kernel<<<dim3(N_DIM / BN, M_DIM / BM), 256, 0, stream>>>(Ap, Bp, out);
    } else {
        u64* xb = (u64*)d_ws;
        u64* wb = xb + (size_t)M_DIM * KC;
        int xgroups = (M_DIM * K_DIM) / 256;
        int wgroups = (N_DIM * K_DIM) / 256;
        pack_sign_kernel<<<xgroups / 4, 256, 0, stream>>>(x, xb, xgroups);
        pack_sign_kernel<<<wgroups / 4, 256, 0, stream>>>(w, wb, wgroups);
        bgemm_kernel<<<dim3(N_DIM / 128, M_DIM / 128), 256, 0, stream>>>(xb, wb, out);
    }
}